// Round 3
// baseline (1107.971 us; speedup 1.0000x reference)
//
#include <hip/hip_runtime.h>
#include <hip/hip_bf16.h>

#define NB 2048
#define NF 6144
#define ND 768
#define NT (NF / 64)  // 96 K-steps per layer

typedef __attribute__((ext_vector_type(8))) __bf16 bf16x8;
typedef __attribute__((ext_vector_type(4))) float f32x4;

// LDS tile: 128 rows x 64 bf16 (128 B rows). 16B-block swizzle
//   blk = (k>>3) ^ (row&7) ^ ((row>>2)&7)
// Hand-verified: fragment ds_read_b128 = 2-way (free); A/B staging
// ds_write_b128 uniform across all 32 banks (minimum cycles).
__device__ __forceinline__ char* lds_addr(char* base, int row, int k) {
  const int blk = ((k >> 3) ^ (row & 7) ^ ((row >> 2) & 7)) & 7;
  return base + row * 128 + (blk << 4) + ((k & 7) << 1);
}

// Non-draining barrier: drain LDS ops (writes must be visible) but leave
// global loads in flight across the barrier (unlike __syncthreads, which
// emits vmcnt(0) and killed the round-2 pipeline).
#define BAR()                                              \
  do {                                                     \
    asm volatile("s_waitcnt lgkmcnt(0)" ::: "memory");     \
    __builtin_amdgcn_sched_barrier(0);                     \
    __builtin_amdgcn_s_barrier();                          \
    __builtin_amdgcn_sched_barrier(0);                     \
  } while (0)

// out[b,d] = sum_l bias[l,d]  (also clears the 0xAA poison deterministically)
__global__ __launch_bounds__(256) void bias_init_kernel(
    const float* __restrict__ bias, const int* __restrict__ lidx,
    float* __restrict__ out) {
  int n = lidx[0] + 1;
  int i = blockIdx.x * 256 + threadIdx.x;
  if (i >= NB * ND) return;
  int d = i % ND;
  float s = 0.f;
  for (int l = 0; l < n; ++l) s += bias[l * ND + d];
  out[i] = s;
}

__global__ __launch_bounds__(256, 2) void gemm_kernel(
    const float* __restrict__ acts, const float* __restrict__ W,
    const int* __restrict__ lidx, float* __restrict__ out) {
  const int l = blockIdx.z;
  if (l > lidx[0]) return;  // uniform exit before any barrier

  const int brow = blockIdx.x * 128;
  const int ncol = blockIdx.y * 128;

  // double-buffered: [buf][A(16KB) | B(16KB)]
  __shared__ char cbuf[2][32768];

  const int tid = threadIdx.x;
  const int lane = tid & 63;
  const int wid = tid >> 6;
  const int wrow = (wid >> 1) * 64;
  const int wcol = (wid & 1) * 64;

  f32x4 acc[4][4];
#pragma unroll
  for (int i = 0; i < 4; ++i)
#pragma unroll
    for (int j = 0; j < 4; ++j) acc[i][j] = (f32x4){0.f, 0.f, 0.f, 0.f};

  // A staging: thread -> (row = tid>>3 (+32 per pass), 8 consecutive k)
  const int s_arow = tid >> 3;
  const int s_ak = (tid & 7) * 8;
  // B staging: thread -> (4 consecutive d, 8 consecutive k)
  const int s_bd = (tid & 31) * 4;
  const int s_bk = (tid >> 5) * 8;

  const float* Aptr =
      acts + (size_t)l * NB * NF + (size_t)(brow + s_arow) * NF + s_ak;
  const float* Bptr =
      W + (size_t)l * NF * ND + (size_t)s_bk * ND + (ncol + s_bd);

  // two named register sets (static indexing only)
  float4 av0[4][2], bv0[8];
  float4 av1[4][2], bv1[8];

#define LOADS(av, bv, kb)                                                 \
  do {                                                                    \
    _Pragma("unroll") for (int p = 0; p < 4; ++p) {                       \
      av[p][0] = *(const float4*)(Aptr + (size_t)(32 * p) * NF + (kb));   \
      av[p][1] = *(const float4*)(Aptr + (size_t)(32 * p) * NF + (kb) + 4); \
    }                                                                     \
    _Pragma("unroll") for (int j = 0; j < 8; ++j)                         \
      bv[j] = *(const float4*)(Bptr + (size_t)((kb) + j) * ND);           \
  } while (0)

#define STORE(av, bv, buf)                                                \
  do {                                                                    \
    char* cA_ = cbuf[buf];                                                \
    char* cB_ = cbuf[buf] + 16384;                                        \
    _Pragma("unroll") for (int p = 0; p < 4; ++p) {                       \
      bf16x8 h;                                                           \
      h[0] = (__bf16)av[p][0].x; h[1] = (__bf16)av[p][0].y;               \
      h[2] = (__bf16)av[p][0].z; h[3] = (__bf16)av[p][0].w;               \
      h[4] = (__bf16)av[p][1].x; h[5] = (__bf16)av[p][1].y;               \
      h[6] = (__bf16)av[p][1].z; h[7] = (__bf16)av[p][1].w;               \
      *(bf16x8*)lds_addr(cA_, s_arow + 32 * p, s_ak) = h;                 \
    }                                                                     \
    _Pragma("unroll") for (int dd = 0; dd < 4; ++dd) {                    \
      bf16x8 h;                                                           \
      _Pragma("unroll") for (int j = 0; j < 8; ++j)                       \
        h[j] = (__bf16)bv[j][dd];                                         \
      *(bf16x8*)lds_addr(cB_, s_bd + dd, s_bk) = h;                       \
    }                                                                     \
  } while (0)

#define KSTEP(buf, s)                                                     \
  do {                                                                    \
    char* cA_ = cbuf[buf];                                                \
    char* cB_ = cbuf[buf] + 16384;                                        \
    const int kk = (s)*32 + (lane >> 4) * 8;                              \
    bf16x8 aF[4], bF[4];                                                  \
    _Pragma("unroll") for (int mi = 0; mi < 4; ++mi)                      \
      aF[mi] = *(const bf16x8*)lds_addr(cA_, wrow + mi * 16 + (lane & 15), kk); \
    _Pragma("unroll") for (int ni = 0; ni < 4; ++ni)                      \
      bF[ni] = *(const bf16x8*)lds_addr(cB_, wcol + ni * 16 + (lane & 15), kk); \
    _Pragma("unroll") for (int mi = 0; mi < 4; ++mi)                      \
      _Pragma("unroll") for (int ni = 0; ni < 4; ++ni)                    \
        acc[mi][ni] = __builtin_amdgcn_mfma_f32_16x16x32_bf16(            \
            aF[mi], bF[ni], acc[mi][ni], 0, 0, 0);                        \
  } while (0)

  // ---- pipeline prologue ----
  LOADS(av0, bv0, 0);
  STORE(av0, bv0, 0);      // waits its own loads (startup only)
  LOADS(av1, bv1, 64);     // slab 1 in flight

  // ---- main loop: 2 K-steps per trip, one non-draining barrier each ----
  for (int u = 0; u < NT / 2; ++u) {
    // t = 2u : read buf0; store slab 2u+1 -> buf1; issue slab 2u+2
    BAR();
    KSTEP(0, 0);
    STORE(av1, bv1, 1);                        // counted vmcnt via reg deps
    KSTEP(0, 1);
    if (2 * u + 2 < NT) LOADS(av0, bv0, (2 * u + 2) * 64);

    // t = 2u+1 : read buf1; store slab 2u+2 -> buf0; issue slab 2u+3
    BAR();
    KSTEP(1, 0);
    if (2 * u + 2 < NT) STORE(av0, bv0, 0);
    KSTEP(1, 1);
    if (2 * u + 3 < NT) LOADS(av1, bv1, (2 * u + 3) * 64);
  }

#undef LOADS
#undef STORE
#undef KSTEP

  // ---- epilogue: atomic accumulate (12 layer-blocks collide per output) ----
  // C/D layout (m89-verified): col = lane&15, row = (lane>>4)*4 + j
  const int orow = brow + wrow + ((lane >> 4) << 2);
  const int ocol = ncol + wcol + (lane & 15);
#pragma unroll
  for (int mi = 0; mi < 4; ++mi)
#pragma unroll
    for (int ni = 0; ni < 4; ++ni)
#pragma unroll
      for (int j = 0; j < 4; ++j)
        atomicAdd(out + (size_t)(orow + mi * 16 + j) * ND + (ocol + ni * 16),
                  acc[mi][ni][j]);
}

extern "C" void kernel_launch(void* const* d_in, const int* in_sizes, int n_in,
                              void* d_out, int out_size, void* d_ws, size_t ws_size,
                              hipStream_t stream) {
  const float* acts = (const float*)d_in[0];
  const float* W    = (const float*)d_in[1];
  const float* bias = (const float*)d_in[2];
  const int*   lidx = (const int*)d_in[3];
  float* out = (float*)d_out;

  const int L = in_sizes[0] / (NB * NF);  // 12

  bias_init_kernel<<<dim3((NB * ND + 255) / 256), 256, 0, stream>>>(bias, lidx, out);
  gemm_kernel<<<dim3(NB / 128, ND / 128, L), 256, 0, stream>>>(acts, W, lidx, out);
}

// Round 4
// 511.436 us; speedup vs baseline: 2.1664x; 2.1664x over previous
//
#include <hip/hip_runtime.h>
#include <hip/hip_bf16.h>

#define NB 2048
#define NF 6144
#define ND 768
#define NT (NF / 64)  // 96 K-steps per layer

typedef __attribute__((ext_vector_type(8))) __bf16 bf16x8;
typedef __attribute__((ext_vector_type(4))) float f32x4;

// LDS tile: 128 rows x 64 bf16 (128 B rows). 16B-block swizzle
//   blk = (k>>3) ^ (row&7) ^ ((row>>2)&7)
// Hand-verified: fragment ds_read_b128 = 2-way (free); A/B staging
// ds_write_b128 uniform across all 32 banks (minimum cycles).
__device__ __forceinline__ char* lds_addr(char* base, int row, int k) {
  const int blk = ((k >> 3) ^ (row & 7) ^ ((row >> 2) & 7)) & 7;
  return base + row * 128 + (blk << 4) + ((k & 7) << 1);
}

// Non-draining barrier: drain LDS ops (ds_writes must be visible across the
// workgroup) but leave global loads in flight (vmcnt NOT drained — the whole
// point; __syncthreads would emit vmcnt(0)).
#define BAR()                                              \
  do {                                                     \
    asm volatile("s_waitcnt lgkmcnt(0)" ::: "memory");     \
    __builtin_amdgcn_sched_barrier(0);                     \
    __builtin_amdgcn_s_barrier();                          \
    __builtin_amdgcn_sched_barrier(0);                     \
  } while (0)

// out[b,d] = sum_l bias[l,d]  (also clears the 0xAA poison deterministically)
__global__ __launch_bounds__(256) void bias_init_kernel(
    const float* __restrict__ bias, const int* __restrict__ lidx,
    float* __restrict__ out) {
  int n = lidx[0] + 1;
  int i = blockIdx.x * 256 + threadIdx.x;
  if (i >= NB * ND) return;
  int d = i % ND;
  float s = 0.f;
  for (int l = 0; l < n; ++l) s += bias[l * ND + d];
  out[i] = s;
}

__global__ __launch_bounds__(256, 2) void gemm_kernel(
    const float* __restrict__ acts, const float* __restrict__ W,
    const int* __restrict__ lidx, float* __restrict__ out) {
  const int l = blockIdx.z;
  if (l > lidx[0]) return;  // uniform exit before any barrier

  const int brow = blockIdx.x * 128;
  const int ncol = blockIdx.y * 128;

  // double-buffered: [buf][A(16KB) | B(16KB)]
  __shared__ char cbuf[2][32768];

  const int tid = threadIdx.x;
  const int lane = tid & 63;
  const int wid = tid >> 6;
  const int wrow = (wid >> 1) * 64;
  const int wcol = (wid & 1) * 64;

  f32x4 acc[4][4];
#pragma unroll
  for (int i = 0; i < 4; ++i)
#pragma unroll
    for (int j = 0; j < 4; ++j) acc[i][j] = (f32x4){0.f, 0.f, 0.f, 0.f};

  // A staging: thread -> (row = tid>>3 (+32 per pass), 8 consecutive k)
  const int s_arow = tid >> 3;
  const int s_ak = (tid & 7) * 8;
  // B staging: thread -> (4 consecutive d, 8 consecutive k)
  const int s_bd = (tid & 31) * 4;
  const int s_bk = (tid >> 5) * 8;

  const float* Aptr =
      acts + (size_t)l * NB * NF + (size_t)(brow + s_arow) * NF + s_ak;
  const float* Bptr =
      W + (size_t)l * NF * ND + (size_t)s_bk * ND + (ncol + s_bd);

  // SINGLE register staging set (round-3's double set spilled to scratch)
  float4 av[4][2];  // 4 row-passes x 8 k (fp32)
  float4 bv[8];     // 8 k-rows x 4 d (fp32)

  auto LOADS = [&](int kb) {
#pragma unroll
    for (int p = 0; p < 4; ++p) {
      av[p][0] = *(const float4*)(Aptr + (size_t)(32 * p) * NF + kb);
      av[p][1] = *(const float4*)(Aptr + (size_t)(32 * p) * NF + kb + 4);
    }
#pragma unroll
    for (int j = 0; j < 8; ++j)
      bv[j] = *(const float4*)(Bptr + (size_t)(kb + j) * ND);
  };

  auto STORE = [&](int buf) {
    char* cA_ = cbuf[buf];
    char* cB_ = cbuf[buf] + 16384;
#pragma unroll
    for (int p = 0; p < 4; ++p) {
      bf16x8 h;
      h[0] = (__bf16)av[p][0].x; h[1] = (__bf16)av[p][0].y;
      h[2] = (__bf16)av[p][0].z; h[3] = (__bf16)av[p][0].w;
      h[4] = (__bf16)av[p][1].x; h[5] = (__bf16)av[p][1].y;
      h[6] = (__bf16)av[p][1].z; h[7] = (__bf16)av[p][1].w;
      *(bf16x8*)lds_addr(cA_, s_arow + 32 * p, s_ak) = h;
    }
#pragma unroll
    for (int dd = 0; dd < 4; ++dd) {
      bf16x8 h;
#pragma unroll
      for (int j = 0; j < 8; ++j) h[j] = (__bf16)bv[j][dd];
      *(bf16x8*)lds_addr(cB_, s_bd + dd, s_bk) = h;
    }
  };

  auto KSTEP = [&](int buf, int s) {
    char* cA_ = cbuf[buf];
    char* cB_ = cbuf[buf] + 16384;
    const int kk = s * 32 + (lane >> 4) * 8;
    bf16x8 aF[4], bF[4];
#pragma unroll
    for (int mi = 0; mi < 4; ++mi)
      aF[mi] = *(const bf16x8*)lds_addr(cA_, wrow + mi * 16 + (lane & 15), kk);
#pragma unroll
    for (int ni = 0; ni < 4; ++ni)
      bF[ni] = *(const bf16x8*)lds_addr(cB_, wcol + ni * 16 + (lane & 15), kk);
#pragma unroll
    for (int mi = 0; mi < 4; ++mi)
#pragma unroll
      for (int ni = 0; ni < 4; ++ni)
        acc[mi][ni] = __builtin_amdgcn_mfma_f32_16x16x32_bf16(
            aF[mi], bF[ni], acc[mi][ni], 0, 0, 0);
  };

  // ---- pipeline prologue ----
  LOADS(0);
  STORE(0);            // waits its own loads (startup only)
  LOADS(64);           // slab 1 in flight across the whole first K-step

  // ---- main loop: one non-draining barrier per K-step, LDS double-buffer ---
  // Hazards (hand-checked): BAR at top of iter t guarantees buf[t&1] fully
  // written (STORE in iter t-1) and buf[t^1] fully read (KSTEPs in iter t-1),
  // both drained by lgkmcnt(0). Global loads stay in flight across BAR.
  for (int t = 0; t < NT; ++t) {
    BAR();
    const int cur = t & 1;
    KSTEP(cur, 0);
    KSTEP(cur, 1);
    if (t + 1 < NT) STORE(cur ^ 1);        // hw-counted vmcnt via reg deps
    if (t + 2 < NT) LOADS((t + 2) * 64);   // issue; consumed next iteration
  }

  // ---- epilogue: atomic accumulate (12 layer-blocks collide per output) ----
  // C/D layout (m89-verified): col = lane&15, row = (lane>>4)*4 + j
  const int orow = brow + wrow + ((lane >> 4) << 2);
  const int ocol = ncol + wcol + (lane & 15);
#pragma unroll
  for (int mi = 0; mi < 4; ++mi)
#pragma unroll
    for (int ni = 0; ni < 4; ++ni)
#pragma unroll
      for (int j = 0; j < 4; ++j)
        atomicAdd(out + (size_t)(orow + mi * 16 + j) * ND + (ocol + ni * 16),
                  acc[mi][ni][j]);
}

extern "C" void kernel_launch(void* const* d_in, const int* in_sizes, int n_in,
                              void* d_out, int out_size, void* d_ws, size_t ws_size,
                              hipStream_t stream) {
  const float* acts = (const float*)d_in[0];
  const float* W    = (const float*)d_in[1];
  const float* bias = (const float*)d_in[2];
  const int*   lidx = (const int*)d_in[3];
  float* out = (float*)d_out;

  const int L = in_sizes[0] / (NB * NF);  // 12

  bias_init_kernel<<<dim3((NB * ND + 255) / 256), 256, 0, stream>>>(bias, lidx, out);
  gemm_kernel<<<dim3(NB / 128, ND / 128, L), 256, 0, stream>>>(acts, W, lidx, out);
}